// Round 3
// baseline (457.103 us; speedup 1.0000x reference)
//
#include <hip/hip_runtime.h>
#include <math.h>

#define N_TOK   16384
#define D_MODEL 4096
#define N_EXP   16
#define N_SEL   4
#define WELEM   (N_EXP * D_MODEL)   // 65536 per weight matrix

typedef __bf16 bf16x8 __attribute__((ext_vector_type(8)));
typedef float  f32x4  __attribute__((ext_vector_type(4)));

#define MFMA(a, b, c) __builtin_amdgcn_mfma_f32_16x16x32_bf16((a), (b), (c), 0, 0, 0)
#define AS1 __attribute__((address_space(1)))
#define AS3 __attribute__((address_space(3)))

// ---------------------------------------------------------------------------
// Split w1/wn into bf16 (hi, mid, lo) triplets: w ≈ hi + mid + lo.
// Layout in wbuf: [w1hi][w1mid][w1lo][wnhi][wnmid][wnlo].
// ---------------------------------------------------------------------------
__global__ __launch_bounds__(256) void wprep_kernel(const float* __restrict__ w1,
                                                    const float* __restrict__ wn,
                                                    __bf16* __restrict__ wbuf)
{
    const int i = blockIdx.x * 256 + threadIdx.x;   // 0..65535
    {
        const float v = w1[i];
        const __bf16 h = (__bf16)v;  const float r1 = v - (float)h;
        const __bf16 m = (__bf16)r1; const float r2 = r1 - (float)m;
        wbuf[i] = h; wbuf[WELEM + i] = m; wbuf[2 * WELEM + i] = (__bf16)r2;
    }
    {
        const float v = wn[i];
        const __bf16 h = (__bf16)v;  const float r1 = v - (float)h;
        const __bf16 m = (__bf16)r1; const float r2 = r1 - (float)m;
        wbuf[3 * WELEM + i] = h; wbuf[4 * WELEM + i] = m; wbuf[5 * WELEM + i] = (__bf16)r2;
    }
}

// ---------------------------------------------------------------------------
// Fused gate kernel. Block = 64 tokens, 4 waves; wave w owns tokens
// [w*16, w*16+16) x full K=4096. x streamed global->LDS async, double-buffered
// 128-col stages, XOR-swizzled via the *global* address (LDS dest is fixed
// wave-uniform+lane*16): LDS float4 slot (tl, k4s) holds x[tl][(k4s^tl)*4..+4].
// A-frag (weights): A[m=lane&15][k=q*8+j]; B-frag (x): B[k=q*8+j][n=lane&15];
// C/D: col(token)=lane&15, row(expert)=q*4+reg.
// ---------------------------------------------------------------------------
__device__ __forceinline__ void stage_load(const float* __restrict__ x,
                                           float4* xs, int buf, int w, int l,
                                           int t0, int kbase)
{
    #pragma unroll
    for (int j = 0; j < 8; ++j) {
        const int tl     = j * 2 + (l >> 5);        // token-local 0..15
        const int k4slot = l & 31;                  // float4 slot within row
        const int k4data = k4slot ^ tl;             // content swizzle
        const float* g = x + (size_t)(t0 + w * 16 + tl) * D_MODEL + kbase + k4data * 4;
        float4* lbase = xs + buf * 2048 + w * 512 + j * 64;   // wave-uniform
        __builtin_amdgcn_global_load_lds((const AS1 void*)(const void*)g,
                                         (AS3 void*)(void*)lbase, 16, 0, 0);
    }
}

__device__ __forceinline__ void split3(const float4 a, const float4 b,
                                       bf16x8& h, bf16x8& m, bf16x8& lo)
{
    const float v[8] = {a.x, a.y, a.z, a.w, b.x, b.y, b.z, b.w};
    #pragma unroll
    for (int j = 0; j < 8; ++j) {
        const __bf16 hh = (__bf16)v[j]; const float r1 = v[j] - (float)hh;
        const __bf16 mm = (__bf16)r1;   const float r2 = r1 - (float)mm;
        h[j] = hh; m[j] = mm; lo[j] = (__bf16)r2;
    }
}

__global__ __launch_bounds__(256, 2) void gate_kernel(
    const float* __restrict__ x, const __bf16* __restrict__ wbuf,
    const float* __restrict__ w2, const float* __restrict__ noise,
    float* __restrict__ out, float* __restrict__ g_imp, float* __restrict__ g_load)
{
    __shared__ float4 xs[4096];                 // 2 bufs x 4 waves x 512 slots = 64 KB
    __shared__ float dsum[4][16][33];           // padded: stride 33 -> conflict-free
    __shared__ float s_imp[N_EXP], s_ld[N_EXP];

    const int tid = threadIdx.x;
    const int l   = tid & 63;
    const int w   = tid >> 6;
    const int ml  = l & 15;      // expert-row (A) / token (B,C)
    const int q   = l >> 4;      // k-group
    const int t0  = blockIdx.x * 64;

    const __bf16* w1h = wbuf;
    const __bf16* w1m = wbuf + WELEM;
    const __bf16* w1l = wbuf + 2 * WELEM;
    const __bf16* wnh = wbuf + 3 * WELEM;
    const __bf16* wnm = wbuf + 4 * WELEM;
    const __bf16* wnl = wbuf + 5 * WELEM;
    const int woff = ml * D_MODEL + q * 8;

    f32x4 c1 = {0.f, 0.f, 0.f, 0.f};
    f32x4 c2 = {0.f, 0.f, 0.f, 0.f};

    stage_load(x, xs, 0, w, l, t0, 0);
    if (tid < N_EXP) { s_imp[tid] = 0.f; s_ld[tid] = 0.f; }
    __syncthreads();    // drains preload (vmcnt(0) before s_barrier)

    for (int s = 0; s < 32; ++s) {
        if (s < 31) stage_load(x, xs, (s + 1) & 1, w, l, t0, (s + 1) * 128);

        const int kbase = s * 128;
        const int xb    = (s & 1) * 2048 + w * 512 + ml * 32;
        #pragma unroll
        for (int step = 0; step < 4; ++step) {
            const int kq = step * 8 + q * 2;                 // float4 slot of k
            const float4 va = xs[xb + (kq ^ ml)];
            const float4 vb = xs[xb + ((kq + 1) ^ ml)];
            bf16x8 xh, xm, xl;
            split3(va, vb, xh, xm, xl);

            const int wo = woff + kbase + step * 32;
            const bf16x8 a1h = *(const bf16x8*)(w1h + wo);
            const bf16x8 a1m = *(const bf16x8*)(w1m + wo);
            const bf16x8 a1l = *(const bf16x8*)(w1l + wo);
            const bf16x8 a2h = *(const bf16x8*)(wnh + wo);
            const bf16x8 a2m = *(const bf16x8*)(wnm + wo);
            const bf16x8 a2l = *(const bf16x8*)(wnl + wo);

            c1 = MFMA(a1h, xh, c1); c1 = MFMA(a1h, xm, c1); c1 = MFMA(a1m, xh, c1);
            c1 = MFMA(a1h, xl, c1); c1 = MFMA(a1l, xh, c1); c1 = MFMA(a1m, xm, c1);
            c2 = MFMA(a2h, xh, c2); c2 = MFMA(a2h, xm, c2); c2 = MFMA(a2m, xh, c2);
            c2 = MFMA(a2h, xl, c2); c2 = MFMA(a2l, xh, c2); c2 = MFMA(a2m, xm, c2);
        }
        __syncthreads();   // waits this iter's loads (overlapped w/ compute) + LDS reads
    }

    #pragma unroll
    for (int r = 0; r < 4; ++r) {
        dsum[w][ml][q * 4 + r]      = c1[r];
        dsum[w][ml][16 + q * 4 + r] = c2[r];
    }
    __syncthreads();

    // ---- per-token epilogue: lanes 0..15 of each wave ----
    if (ml == l) {   // l < 16
        const int t = t0 + w * 16 + ml;
        float dot[32];
        #pragma unroll
        for (int e = 0; e < 32; ++e) dot[e] = dsum[w][ml][e];

        float th[N_EXP], nc[N_EXP];
        #pragma unroll
        for (int e = 0; e < N_EXP; ++e) th[e] = tanhf(dot[e]);
        #pragma unroll
        for (int e = 0; e < N_EXP; ++e) {
            const float v = dot[N_EXP + e];
            nc[e] = fmaxf(v, 0.f) + log1pf(expf(-fabsf(v))) + 0.01f;
        }

        float lg[N_EXP];
        #pragma unroll
        for (int f = 0; f < N_EXP; ++f) {
            float s = 0.f;
            #pragma unroll
            for (int e = 0; e < N_EXP; ++e) s = fmaf(th[e], w2[f * 16 + e], s);
            lg[f] = s;
        }

        float ln[N_EXP], v[N_EXP];
        {
            const float4* nz = (const float4*)(noise + (size_t)t * 16);
            const float4 n0 = nz[0], n1 = nz[1], n2 = nz[2], n3 = nz[3];
            const float nzv[16] = {n0.x, n0.y, n0.z, n0.w, n1.x, n1.y, n1.z, n1.w,
                                   n2.x, n2.y, n2.z, n2.w, n3.x, n3.y, n3.z, n3.w};
            #pragma unroll
            for (int e = 0; e < N_EXP; ++e) {
                ln[e] = nzv[e] * nc[e];
                v[e]  = lg[e] + ln[e];
            }
        }

        // top-5 selection (ties -> lowest index, matching lax.top_k)
        float tv[5]; int ti[5];
        #pragma unroll
        for (int j = 0; j < 5; ++j) {
            float best = -INFINITY; int bi = 0;
            #pragma unroll
            for (int e = 0; e < N_EXP; ++e) {
                bool taken = false;
                #pragma unroll
                for (int jj = 0; jj < 5; ++jj)
                    if (jj < j) taken = taken || (ti[jj] == e);
                if (!taken && v[e] > best) { best = v[e]; bi = e; }
            }
            tv[j] = best; ti[j] = bi;
        }

        const float mx = tv[0];
        float ex[4], ssum = 0.f;
        #pragma unroll
        for (int j = 0; j < 4; ++j) { ex[j] = expf(tv[j] - mx); ssum += ex[j]; }
        const float inv = 1.f / ssum;
        float sc[4];
        #pragma unroll
        for (int j = 0; j < 4; ++j) sc[j] = ex[j] * inv;

        #pragma unroll
        for (int j = 0; j < 4; ++j) atomicAdd(&s_imp[ti[j]], sc[j]);

        const float thr_in = tv[4], thr_out = tv[3];
        #pragma unroll
        for (int e = 0; e < N_EXP; ++e) {
            const bool  is_in = ln[e] > thr_in;
            const float thr   = is_in ? thr_in : thr_out;
            const float z     = (lg[e] - thr) / nc[e];
            const float prob  = 0.5f * (1.f + erff(z * 0.70710678118654752f));
            atomicAdd(&s_ld[e], prob);
        }

        ((float4*)out)[t] = make_float4((float)ti[0], (float)ti[1],
                                        (float)ti[2], (float)ti[3]);
        ((float4*)(out + N_TOK * N_SEL))[t] = make_float4(sc[0], sc[1], sc[2], sc[3]);
    }
    __syncthreads();
    if (tid < N_EXP)            atomicAdd(&g_imp[tid], s_imp[tid]);
    else if (tid < 2 * N_EXP)   atomicAdd(&g_load[tid - N_EXP], s_ld[tid - N_EXP]);
}

// ---------------------------------------------------------------------------
// gate loss = lambda * (cv2(importance) + cv2(load))
// ---------------------------------------------------------------------------
__global__ void loss_kernel(const float* __restrict__ g_imp,
                            const float* __restrict__ g_load,
                            float* __restrict__ out)
{
    if (threadIdx.x == 0 && blockIdx.x == 0) {
        double mi = 0.0, ml = 0.0;
        for (int e = 0; e < N_EXP; ++e) { mi += g_imp[e]; ml += g_load[e]; }
        mi /= N_EXP; ml /= N_EXP;
        double vi = 0.0, vl = 0.0;
        for (int e = 0; e < N_EXP; ++e) {
            const double di = g_imp[e] - mi;  vi += di * di;
            const double dl = g_load[e] - ml; vl += dl * dl;
        }
        vi /= (N_EXP - 1); vl /= (N_EXP - 1);
        const double ci = vi / (mi * mi + 1e-10);
        const double cl = vl / (ml * ml + 1e-10);
        out[N_TOK * N_SEL * 2] = (float)(0.01 * (ci + cl));
    }
}

// ---------------------------------------------------------------------------
extern "C" void kernel_launch(void* const* d_in, const int* in_sizes, int n_in,
                              void* d_out, int out_size, void* d_ws, size_t ws_size,
                              hipStream_t stream)
{
    const float* x     = (const float*)d_in[0];
    const float* w1    = (const float*)d_in[1];
    const float* w2    = (const float*)d_in[2];
    const float* wn    = (const float*)d_in[3];
    const float* noise = (const float*)d_in[4];
    float* out = (float*)d_out;

    __bf16* wbuf   = (__bf16*)d_ws;                             // 768 KB
    float*  g_imp  = (float*)((char*)d_ws + (1 << 20));         // @ 1 MB
    float*  g_load = g_imp + N_EXP;

    hipMemsetAsync(g_imp, 0, 2 * N_EXP * sizeof(float), stream);

    wprep_kernel<<<WELEM / 256, 256, 0, stream>>>(w1, wn, wbuf);
    gate_kernel<<<N_TOK / 64, 256, 0, stream>>>(x, wbuf, w2, noise, out,
                                                g_imp, g_load);
    loss_kernel<<<1, 64, 0, stream>>>(g_imp, g_load, out);
}